// Round 1
// baseline (475.355 us; speedup 1.0000x reference)
//
#include <hip/hip_runtime.h>
#include <stdint.h>

#define S_  8
#define D_  2048
#define B_  2
#define N_  1024
#define SD_ 16384
#define ROWU 12   // 12 u32 = 24 bf16 per packed weight row (22 used)
#define G_  2     // n-values per block

__device__ __forceinline__ unsigned pack_bf16_rne(float a, float b) {
    unsigned ua = __float_as_uint(a);
    unsigned ub = __float_as_uint(b);
    ua += 0x7FFFu + ((ua >> 16) & 1u);   // round-to-nearest-even
    ub += 0x7FFFu + ((ub >> 16) & 1u);
    return (ua >> 16) | (ub & 0xFFFF0000u);
}

// Pack W'[i][j] = (gamma[i]+1) * [W_alpha | W_beta][i][j] as bf16, 24 per row.
extern "C" __global__ void krom_prep(const float* __restrict__ gamma,
                                     const float* __restrict__ Wa,
                                     const float* __restrict__ Wb,
                                     unsigned* __restrict__ Wp)
{
    int i = blockIdx.x * 256 + threadIdx.x;
    if (i >= SD_) return;
    float g = gamma[i] + 1.0f;
    float w[24];
#pragma unroll
    for (int j = 0; j < 14; ++j) w[j] = g * Wa[i * 14 + j];
#pragma unroll
    for (int j = 0; j < 8; ++j)  w[14 + j] = g * Wb[i * 8 + j];
    w[22] = 0.0f; w[23] = 0.0f;
#pragma unroll
    for (int k = 0; k < 12; ++k)
        Wp[(size_t)i * ROWU + k] = pack_bf16_rne(w[2 * k], w[2 * k + 1]);
}

extern "C" __global__ void __launch_bounds__(256, 2)
krom_main(const float* __restrict__ res,
          const unsigned* __restrict__ Wp,
          const float* __restrict__ sa,     // static_alpha[14]
          const float* __restrict__ pre_s,  // pre_branch_scale[1]
          const float* __restrict__ res_s,  // residual_scale[1]
          const float* __restrict__ sb,     // static_beta[8]
          const float* __restrict__ hps,    // h_post_scale[1]
          float* __restrict__ out)
{
    const int tid = threadIdx.x;
    const int blk = blockIdx.x;           // 0..1023
    const int b   = blk >> 9;             // 512 n-pairs per b
    const int n0  = (blk & 511) * G_;
    const int d0  = tid << 3;             // 8 d-values per thread

    // ---- load r into registers: r[n][s][k] = residuals[(b*8+s), n0+n, d0+k]
    float r[G_][S_][8];
#pragma unroll
    for (int n = 0; n < G_; ++n) {
#pragma unroll
        for (int s = 0; s < S_; ++s) {
            const float* p = res + (((size_t)(b * S_ + s) * N_ + (n0 + n)) * D_ + d0);
            const float4 v0 = *reinterpret_cast<const float4*>(p);
            const float4 v1 = *reinterpret_cast<const float4*>(p + 4);
            r[n][s][0] = v0.x; r[n][s][1] = v0.y; r[n][s][2] = v0.z; r[n][s][3] = v0.w;
            r[n][s][4] = v1.x; r[n][s][5] = v1.y; r[n][s][6] = v1.z; r[n][s][7] = v1.w;
        }
    }

    // ---- accumulators: acc[n][0..21] = matvec partials, acc[n][22] = ssq
    float acc[G_][23];
#pragma unroll
    for (int n = 0; n < G_; ++n)
#pragma unroll
        for (int j = 0; j < 23; ++j) acc[n][j] = 0.0f;

#pragma unroll
    for (int n = 0; n < G_; ++n)
#pragma unroll
        for (int s = 0; s < S_; ++s)
#pragma unroll
            for (int k = 0; k < 8; ++k)
                acc[n][22] = fmaf(r[n][s][k], r[n][s][k], acc[n][22]);

    // ---- mat-vec: for each owned i = s*2048 + d0 + k, read 22 bf16 weights
#pragma unroll
    for (int s = 0; s < S_; ++s) {
#pragma unroll
        for (int k = 0; k < 8; ++k) {
            const uint4* rp = reinterpret_cast<const uint4*>(
                Wp + (size_t)(s * D_ + d0 + k) * ROWU);
            uint4 u0 = rp[0], u1 = rp[1], u2 = rp[2];
            unsigned uu[11] = {u0.x, u0.y, u0.z, u0.w,
                               u1.x, u1.y, u1.z, u1.w,
                               u2.x, u2.y, u2.z};
#pragma unroll
            for (int q = 0; q < 11; ++q) {
                float w0 = __uint_as_float(uu[q] << 16);
                float w1 = __uint_as_float(uu[q] & 0xFFFF0000u);
#pragma unroll
                for (int n = 0; n < G_; ++n) {
                    acc[n][2 * q]     = fmaf(r[n][s][k], w0, acc[n][2 * q]);
                    acc[n][2 * q + 1] = fmaf(r[n][s][k], w1, acc[n][2 * q + 1]);
                }
            }
        }
    }

    // ---- block-wide reduction of 46 partials
    __shared__ float red[4][G_][23];
    __shared__ float fin[G_][23];
#pragma unroll
    for (int n = 0; n < G_; ++n)
#pragma unroll
        for (int j = 0; j < 23; ++j) {
            float v = acc[n][j];
#pragma unroll
            for (int m = 1; m < 64; m <<= 1) v += __shfl_xor(v, m, 64);
            acc[n][j] = v;
        }
    const int wave = tid >> 6, lane = tid & 63;
    if (lane == 0) {
#pragma unroll
        for (int n = 0; n < G_; ++n)
#pragma unroll
            for (int j = 0; j < 23; ++j) red[wave][n][j] = acc[n][j];
    }
    __syncthreads();
    if (tid < G_ * 23) {
        int n = tid / 23, j = tid % 23;
        fin[n][j] = red[0][n][j] + red[1][n][j] + red[2][n][j] + red[3][n][j];
    }
    __syncthreads();

    // ---- tiny epilogue math (2 threads, one per n)
    __shared__ float wpre[G_][S_], bet[G_][S_], pk3[G_][3];
    if (tid < G_) {
        const int n = tid;
        const float inv   = rsqrtf(fmaxf(fin[n][22], 1e-24f));
        const float scale = inv * 128.0f;    // sqrt(16384)
        float c[22];
#pragma unroll
        for (int j = 0; j < 22; ++j) c[j] = fin[n][j] * scale;
        const float ps = pre_s[0], rs = res_s[0], hs = hps[0];
        // w_pre = softmax(ps*c[0:8] + sa[0:8])
        float lg[8], mx = -1e30f;
#pragma unroll
        for (int s = 0; s < 8; ++s) { lg[s] = ps * c[s] + sa[s]; mx = fmaxf(mx, lg[s]); }
        float sum = 0.0f;
#pragma unroll
        for (int s = 0; s < 8; ++s) { lg[s] = expf(lg[s] - mx); sum += lg[s]; }
        const float rsum = 1.0f / sum;
#pragma unroll
        for (int s = 0; s < 8; ++s) wpre[n][s] = lg[s] * rsum;
        // p_k = sigmoid(cr0 - cr1)
#pragma unroll
        for (int k = 0; k < 3; ++k) {
            float a0 = rs * c[8 + 2 * k] + sa[8 + 2 * k];
            float a1 = rs * c[9 + 2 * k] + sa[9 + 2 * k];
            pk3[n][k] = 1.0f / (1.0f + expf(a1 - a0));
        }
        // beta_t = sigmoid(hs*c[14+t] + sb[t])
#pragma unroll
        for (int t = 0; t < 8; ++t)
            bet[n][t] = 1.0f / (1.0f + expf(-(hs * c[14 + t] + sb[t])));
    }
    __syncthreads();

    // ---- M[s][t] = hres[s][t] + beta[t]*w_pre[s]
    __shared__ float Mm[G_][S_][S_];
    if (tid < G_ * 64) {
        const int n = tid >> 6, e = tid & 63, s = e >> 3, t = e & 7;
        float h = 1.0f;
#pragma unroll
        for (int k = 0; k < 3; ++k) {
            int sbit = (s >> (2 - k)) & 1, tbit = (t >> (2 - k)) & 1;
            float pk = pk3[n][k];
            h *= (sbit == tbit) ? pk : (1.0f - pk);
        }
        Mm[n][s][t] = h + bet[n][t] * wpre[n][s];
    }
    __syncthreads();

    // ---- out[(b*8+t), n, d] = sum_s M[s][t] * r[s][d]
#pragma unroll
    for (int n = 0; n < G_; ++n) {
#pragma unroll
        for (int t = 0; t < S_; ++t) {
            float o[8];
#pragma unroll
            for (int k = 0; k < 8; ++k) o[k] = 0.0f;
#pragma unroll
            for (int s = 0; s < S_; ++s) {
                const float m = Mm[n][s][t];
#pragma unroll
                for (int k = 0; k < 8; ++k) o[k] = fmaf(m, r[n][s][k], o[k]);
            }
            float* po = out + (((size_t)(b * S_ + t) * N_ + (n0 + n)) * D_ + d0);
            *reinterpret_cast<float4*>(po)     = make_float4(o[0], o[1], o[2], o[3]);
            *reinterpret_cast<float4*>(po + 4) = make_float4(o[4], o[5], o[6], o[7]);
        }
    }
}

extern "C" void kernel_launch(void* const* d_in, const int* in_sizes, int n_in,
                              void* d_out, int out_size, void* d_ws, size_t ws_size,
                              hipStream_t stream)
{
    (void)in_sizes; (void)n_in; (void)out_size; (void)ws_size;
    const float* residuals = (const float*)d_in[0];
    const float* gamma     = (const float*)d_in[1];
    const float* sa        = (const float*)d_in[2];
    const float* Wa        = (const float*)d_in[3];
    const float* pre_s     = (const float*)d_in[4];
    const float* res_s     = (const float*)d_in[5];
    const float* sb        = (const float*)d_in[6];
    const float* Wb        = (const float*)d_in[7];
    const float* hps       = (const float*)d_in[8];
    unsigned* Wp = (unsigned*)d_ws;   // 16384 * 12 * 4 B = 786 KB

    hipLaunchKernelGGL(krom_prep, dim3(SD_ / 256), dim3(256), 0, stream,
                       gamma, Wa, Wb, Wp);
    hipLaunchKernelGGL(krom_main, dim3(B_ * N_ / G_), dim3(256), 0, stream,
                       residuals, Wp, sa, pre_s, res_s, sb, hps, (float*)d_out);
}

// Round 2
// 443.679 us; speedup vs baseline: 1.0714x; 1.0714x over previous
//
#include <hip/hip_runtime.h>
#include <stdint.h>

#define S_  8
#define D_  2048
#define B_  2
#define N_  1024
#define SD_ 16384
#define JP_ 11    // 11 pairs of bf16 weight columns (22 columns)
#define G_  2     // n-values per block
#define T_  512   // threads per block
#define KD_ 4     // d-values per thread (T_*KD_ == D_)

__device__ __forceinline__ unsigned pack_bf16_rne(float a, float b) {
    unsigned ua = __float_as_uint(a);
    unsigned ub = __float_as_uint(b);
    ua += 0x7FFFu + ((ua >> 16) & 1u);   // round-to-nearest-even
    ub += 0x7FFFu + ((ub >> 16) & 1u);
    return (ua >> 16) | (ub & 0xFFFF0000u);
}

// Pack W'[i][j] = (gamma[i]+1)*[W_alpha|W_beta][i][j] as bf16 pairs in a
// coalescing-friendly layout: Wp[(s*11 + jp)*2048 + d] = (w[2jp], w[2jp+1])
extern "C" __global__ void krom_prep(const float* __restrict__ gamma,
                                     const float* __restrict__ Wa,
                                     const float* __restrict__ Wb,
                                     unsigned* __restrict__ Wp)
{
    int i = blockIdx.x * 256 + threadIdx.x;
    if (i >= SD_) return;
    const int s = i >> 11, d = i & 2047;
    float g = gamma[i] + 1.0f;
    float w[22];
#pragma unroll
    for (int j = 0; j < 14; ++j) w[j] = g * Wa[i * 14 + j];
#pragma unroll
    for (int j = 0; j < 8; ++j)  w[14 + j] = g * Wb[i * 8 + j];
#pragma unroll
    for (int jp = 0; jp < JP_; ++jp)
        Wp[((s * JP_ + jp) << 11) + d] = pack_bf16_rne(w[2 * jp], w[2 * jp + 1]);
}

extern "C" __global__ void __launch_bounds__(T_, 2)
krom_main(const float* __restrict__ res,
          const unsigned* __restrict__ Wp,
          const float* __restrict__ sa,     // static_alpha[14]
          const float* __restrict__ pre_s,  // pre_branch_scale[1]
          const float* __restrict__ res_s,  // residual_scale[1]
          const float* __restrict__ sb,     // static_beta[8]
          const float* __restrict__ hps,    // h_post_scale[1]
          float* __restrict__ out)
{
    const int tid = threadIdx.x;
    const int blk = blockIdx.x;           // 0..1023
    const int b   = blk >> 9;             // 512 n-pairs per b
    const int n0  = (blk & 511) * G_;
    const int d0  = tid * KD_;            // 4 d-values per thread

    // ---- load r into registers: r[n][s][k] = residuals[(b*8+s), n0+n, d0+k]
    float r[G_][S_][KD_];
#pragma unroll
    for (int n = 0; n < G_; ++n) {
#pragma unroll
        for (int s = 0; s < S_; ++s) {
            const float4 v = *reinterpret_cast<const float4*>(
                res + (((size_t)(b * S_ + s) * N_ + (n0 + n)) * D_ + d0));
            r[n][s][0] = v.x; r[n][s][1] = v.y; r[n][s][2] = v.z; r[n][s][3] = v.w;
        }
    }

    // ---- accumulators: acc[n][0..21] = matvec partials, acc[n][22] = ssq
    float acc[G_][23];
#pragma unroll
    for (int n = 0; n < G_; ++n)
#pragma unroll
        for (int j = 0; j < 23; ++j) acc[n][j] = 0.0f;

#pragma unroll
    for (int n = 0; n < G_; ++n)
#pragma unroll
        for (int s = 0; s < S_; ++s)
#pragma unroll
            for (int k = 0; k < KD_; ++k)
                acc[n][22] = fmaf(r[n][s][k], r[n][s][k], acc[n][22]);

    // ---- mat-vec: coalesced uint4 weight loads (4 d's x 1 j-pair each)
#pragma unroll
    for (int s = 0; s < S_; ++s) {
#pragma unroll
        for (int jp = 0; jp < JP_; ++jp) {
            const uint4 u = *reinterpret_cast<const uint4*>(
                Wp + ((s * JP_ + jp) << 11) + d0);
            const unsigned uu[KD_] = {u.x, u.y, u.z, u.w};
#pragma unroll
            for (int k = 0; k < KD_; ++k) {
                const float w0 = __uint_as_float(uu[k] << 16);
                const float w1 = __uint_as_float(uu[k] & 0xFFFF0000u);
#pragma unroll
                for (int n = 0; n < G_; ++n) {
                    acc[n][2 * jp]     = fmaf(r[n][s][k], w0, acc[n][2 * jp]);
                    acc[n][2 * jp + 1] = fmaf(r[n][s][k], w1, acc[n][2 * jp + 1]);
                }
            }
        }
    }

    // ---- block-wide reduction of 46 partials (8 waves)
    __shared__ float red[T_ / 64][G_][23];
    __shared__ float fin[G_][23];
#pragma unroll
    for (int n = 0; n < G_; ++n)
#pragma unroll
        for (int j = 0; j < 23; ++j) {
            float v = acc[n][j];
#pragma unroll
            for (int m = 1; m < 64; m <<= 1) v += __shfl_xor(v, m, 64);
            acc[n][j] = v;
        }
    const int wave = tid >> 6, lane = tid & 63;
    if (lane == 0) {
#pragma unroll
        for (int n = 0; n < G_; ++n)
#pragma unroll
            for (int j = 0; j < 23; ++j) red[wave][n][j] = acc[n][j];
    }
    __syncthreads();
    if (tid < G_ * 23) {
        int n = tid / 23, j = tid % 23;
        float v = 0.0f;
#pragma unroll
        for (int w = 0; w < T_ / 64; ++w) v += red[w][n][j];
        fin[n][j] = v;
    }
    __syncthreads();

    // ---- tiny epilogue math (2 threads, one per n)
    __shared__ float wpre[G_][S_], bet[G_][S_], pk3[G_][3];
    if (tid < G_) {
        const int n = tid;
        const float inv   = rsqrtf(fmaxf(fin[n][22], 1e-24f));
        const float scale = inv * 128.0f;    // sqrt(16384)
        float c[22];
#pragma unroll
        for (int j = 0; j < 22; ++j) c[j] = fin[n][j] * scale;
        const float ps = pre_s[0], rs = res_s[0], hs = hps[0];
        // w_pre = softmax(ps*c[0:8] + sa[0:8])
        float lg[8], mx = -1e30f;
#pragma unroll
        for (int s = 0; s < 8; ++s) { lg[s] = ps * c[s] + sa[s]; mx = fmaxf(mx, lg[s]); }
        float sum = 0.0f;
#pragma unroll
        for (int s = 0; s < 8; ++s) { lg[s] = expf(lg[s] - mx); sum += lg[s]; }
        const float rsum = 1.0f / sum;
#pragma unroll
        for (int s = 0; s < 8; ++s) wpre[n][s] = lg[s] * rsum;
        // p_k = sigmoid(cr0 - cr1)
#pragma unroll
        for (int k = 0; k < 3; ++k) {
            float a0 = rs * c[8 + 2 * k] + sa[8 + 2 * k];
            float a1 = rs * c[9 + 2 * k] + sa[9 + 2 * k];
            pk3[n][k] = 1.0f / (1.0f + expf(a1 - a0));
        }
        // beta_t = sigmoid(hs*c[14+t] + sb[t])
#pragma unroll
        for (int t = 0; t < 8; ++t)
            bet[n][t] = 1.0f / (1.0f + expf(-(hs * c[14 + t] + sb[t])));
    }
    __syncthreads();

    // ---- M[s][t] = hres[s][t] + beta[t]*w_pre[s]
    __shared__ float Mm[G_][S_][S_];
    if (tid < G_ * 64) {
        const int n = tid >> 6, e = tid & 63, s = e >> 3, t = e & 7;
        float h = 1.0f;
#pragma unroll
        for (int k = 0; k < 3; ++k) {
            int sbit = (s >> (2 - k)) & 1, tbit = (t >> (2 - k)) & 1;
            float pk = pk3[n][k];
            h *= (sbit == tbit) ? pk : (1.0f - pk);
        }
        Mm[n][s][t] = h + bet[n][t] * wpre[n][s];
    }
    __syncthreads();

    // ---- out[(b*8+t), n, d] = sum_s M[s][t] * r[s][d]
#pragma unroll
    for (int n = 0; n < G_; ++n) {
#pragma unroll
        for (int t = 0; t < S_; ++t) {
            float o[KD_];
#pragma unroll
            for (int k = 0; k < KD_; ++k) o[k] = 0.0f;
#pragma unroll
            for (int s = 0; s < S_; ++s) {
                const float m = Mm[n][s][t];
#pragma unroll
                for (int k = 0; k < KD_; ++k) o[k] = fmaf(m, r[n][s][k], o[k]);
            }
            float* po = out + (((size_t)(b * S_ + t) * N_ + (n0 + n)) * D_ + d0);
            *reinterpret_cast<float4*>(po) = make_float4(o[0], o[1], o[2], o[3]);
        }
    }
}

extern "C" void kernel_launch(void* const* d_in, const int* in_sizes, int n_in,
                              void* d_out, int out_size, void* d_ws, size_t ws_size,
                              hipStream_t stream)
{
    (void)in_sizes; (void)n_in; (void)out_size; (void)ws_size;
    const float* residuals = (const float*)d_in[0];
    const float* gamma     = (const float*)d_in[1];
    const float* sa        = (const float*)d_in[2];
    const float* Wa        = (const float*)d_in[3];
    const float* pre_s     = (const float*)d_in[4];
    const float* res_s     = (const float*)d_in[5];
    const float* sb        = (const float*)d_in[6];
    const float* hps       = (const float*)d_in[7];
    const float* Wb        = (const float*)d_in[7];
    // NOTE: input order per setup_inputs(): residuals, gamma, static_alpha,
    // W_alpha, pre_branch_scale, residual_scale, static_beta, W_beta, h_post_scale
    sb  = (const float*)d_in[6];
    Wb  = (const float*)d_in[7];
    hps = (const float*)d_in[8];

    unsigned* Wp = (unsigned*)d_ws;   // 11 * 16384 * 4 B = 720 KB

    hipLaunchKernelGGL(krom_prep, dim3(SD_ / 256), dim3(256), 0, stream,
                       gamma, Wa, Wb, Wp);
    hipLaunchKernelGGL(krom_main, dim3(B_ * N_ / G_), dim3(T_), 0, stream,
                       residuals, Wp, sa, pre_s, res_s, sb, hps, (float*)d_out);
}